// Round 10
// baseline (341.784 us; speedup 1.0000x reference)
//
#include <hip/hip_runtime.h>
#include <hip/hip_bf16.h>

#define N_NODES 10000
#define N_EDGES 320000
#define DIM     256
#define N_LAYERS 5
#define N_GRAPHS 128
#define RWSE_K  16
#define GBM 16

typedef __bf16 bf16_t;
typedef bf16_t bf16x8 __attribute__((ext_vector_type(8)));
typedef float  f32x4  __attribute__((ext_vector_type(4)));

__device__ inline ushort f2bf(float f) {
    union { float f; unsigned u; } v; v.f = f;
    unsigned r = v.u + 0x7fff + ((v.u >> 16) & 1);
    return (ushort)(r >> 16);
}
__device__ inline float bfbits2f(unsigned hi16) {
    union { unsigned u; float f; } v; v.u = hi16;
    return v.f;
}

// ---------------- fused setup: embed + edge-count + weight conv + BN fold ----
__global__ __launch_bounds__(256)
void setup_kernel(const int* __restrict__ feat_id,
                  const float* __restrict__ rwse,
                  const int* __restrict__ in_deg,
                  const float* __restrict__ w_val,
                  const float* __restrict__ b_val,
                  const float* __restrict__ w_rwse,
                  const float* __restrict__ b_rwse,
                  const float* __restrict__ deg_emb,
                  ushort* __restrict__ hb,
                  const int* __restrict__ ei, int* __restrict__ cnt_arr,
                  const float* __restrict__ w1, const float* __restrict__ w2,
                  ushort* __restrict__ wt1, ushort* __restrict__ wt2,
                  const float* __restrict__ gamma, const float* __restrict__ beta,
                  const float* __restrict__ mean, const float* __restrict__ var,
                  const float* __restrict__ b2, float* __restrict__ scale,
                  float* __restrict__ shift) {
    __shared__ float r[RWSE_K];
    __shared__ float t[32][33];
    int b = blockIdx.x;
    int tid = threadIdx.x;
    if (b < N_NODES) {
        int i = b, d = tid;
        if (d < RWSE_K) r[d] = rwse[i * RWSE_K + d];
        __syncthreads();
        int hid = feat_id[i] & (DIM - 1);
        int dg = in_deg[i];
        dg = dg < 0 ? 0 : (dg > 1000 ? 1000 : dg);
        float v = w_val[hid * DIM + d] + b_val[d] + b_rwse[d] + deg_emb[dg * DIM + d];
#pragma unroll
        for (int k = 0; k < RWSE_K; ++k) v += r[k] * w_rwse[k * DIM + d];
        hb[i * DIM + d] = f2bf(v);
    } else if (b < 11250) {
        int e = (b - N_NODES) * 256 + tid;
        if (e < N_EDGES) atomicAdd(&cnt_arr[ei[N_EDGES + e]], 1);
    } else if (b < 11890) {
        int w_id = b - 11250;
        int l = w_id >> 7;
        int rem = w_id & 127;
        int mat = rem >> 6;
        int tile = rem & 63;
        const float* W  = (mat ? w2  : w1)  + (size_t)l * DIM * DIM;
        ushort*      Wt = (mat ? wt2 : wt1) + (size_t)l * DIM * DIM;
        int k0 = (tile >> 3) * 32, n0 = (tile & 7) * 32;
        int tx = tid & 31, ty = tid >> 5;
#pragma unroll
        for (int j = 0; j < 4; ++j)
            t[ty + j * 8][tx] = W[(k0 + ty + j * 8) * DIM + n0 + tx];
        __syncthreads();
#pragma unroll
        for (int j = 0; j < 4; ++j)
            Wt[(n0 + ty + j * 8) * DIM + k0 + tx] = f2bf(t[tx][ty + j * 8]);
    } else {
        int l = b - 11890;
        int idx = l * DIM + tid;
        float s = gamma[idx] * rsqrtf(var[idx] + 1e-5f);
        scale[idx] = s;
        shift[idx] = beta[idx] + (b2[idx] - mean[idx]) * s;
    }
}

// exclusive scan of cnt_arr into cur (single block, wave-shuffle based)
__global__ __launch_bounds__(1024)
void scan_kernel(const int* __restrict__ cnt_arr, int* __restrict__ cur, int n) {
    __shared__ int wsum[16];
    __shared__ int carry_sh;
    int tid = threadIdx.x, wave = tid >> 6, lane = tid & 63;
    if (tid == 0) carry_sh = 0;
    __syncthreads();
    for (int base = 0; base < n; base += 1024) {
        int idx = base + tid;
        int v = (idx < n) ? cnt_arr[idx] : 0;
        int s = v;
#pragma unroll
        for (int off = 1; off < 64; off <<= 1) {
            int t = __shfl_up(s, off, 64);
            if (lane >= off) s += t;
        }
        if (lane == 63) wsum[wave] = s;
        __syncthreads();
        if (wave == 0) {
            int ws = (lane < 16) ? wsum[lane] : 0;
#pragma unroll
            for (int off = 1; off < 16; off <<= 1) {
                int t = __shfl_up(ws, off, 64);
                if (lane >= off) ws += t;
            }
            if (lane < 16) wsum[lane] = ws;
        }
        __syncthreads();
        int excl = s - v + (wave ? wsum[wave - 1] : 0) + carry_sh;
        if (idx < n) cur[idx] = excl;
        __syncthreads();
        if (tid == 0) carry_sh += wsum[15];
        __syncthreads();
    }
}

__global__ __launch_bounds__(256)
void fill_kernel(const int* __restrict__ ei, int* __restrict__ cur,
                 int* __restrict__ cs) {
    int e = blockIdx.x * 256 + threadIdx.x;
    if (e < N_EDGES) {
        int d = ei[N_EDGES + e];
        int p = atomicAdd(&cur[d], 1);
        cs[p] = ei[e];
    }
}

// ---------------- fused layer: aggregation + MLP + BN + ReLU ----------------
// Block = 16 rows x 256 cols, 4 waves; grid 625.
// Phase A: SPLIT-D TWO-PASS gather (working set 2.56 MB < 4 MB/XCD L2 to kill
// the capacity thrash R3's counters showed). R9 FIX: the tail-edge __shfl is
// executed by ALL lanes (source lane always active); only the load is guarded.
// GEMM phase: R6-proven BK=64, t overlays As, plain stores.
#define ACCV(v)                                                        \
    acc[0] += bfbits2f((v).x << 16); acc[1] += bfbits2f((v).x & 0xffff0000u); \
    acc[2] += bfbits2f((v).y << 16); acc[3] += bfbits2f((v).y & 0xffff0000u); \
    acc[4] += bfbits2f((v).z << 16); acc[5] += bfbits2f((v).z & 0xffff0000u); \
    acc[6] += bfbits2f((v).w << 16); acc[7] += bfbits2f((v).w & 0xffff0000u);

__global__ __launch_bounds__(256)
void layer_kernel(const ushort* __restrict__ hb_in,
                  const int* __restrict__ cur, const int* __restrict__ cs,
                  const float* __restrict__ eps_gin, int layer,
                  const ushort* __restrict__ Wt1, const float* __restrict__ b1,
                  const ushort* __restrict__ Wt2,
                  const float* __restrict__ bnsc, const float* __restrict__ bnsh,
                  float* __restrict__ outF, ushort* __restrict__ outB) {
    __shared__ __align__(16) ushort As[GBM][DIM + 8];   // gather out / t overlay
    __shared__ __align__(16) ushort Bs[DIM][72];        // 256x64 weight slice
    int tx = threadIdx.x;
    int row0 = blockIdx.x * GBM;
    int wave = tx >> 6, lane = tx & 63, quad = lane >> 4, l16 = lane & 15;
    int q = lane >> 4, ql = lane & 15;     // quarter split for gather
    int wc = wave * 64;
    int srow2 = tx >> 3;           // 0..31
    int skol2 = (tx & 7) * 8;      // 0,8,...,56
    const uint4* hb4 = (const uint4*)hb_in;   // row = 32 uint4
    float sc = 1.0f + eps_gin[layer];

    // hoist edge boundaries (wave-uniform)
    int e0s[4], e1s[4];
#pragma unroll
    for (int n = 0; n < 4; ++n) {
        int i = row0 + wave * 4 + n;
        e0s[n] = i ? cur[i - 1] : 0;
        e1s[n] = cur[i];
    }

    // ---- Phase A: two column-passes over this block's 16 rows ----
#pragma unroll
    for (int p = 0; p < 2; ++p) {
        const uint4* hbp = hb4 + p * 16;   // half-row base (16 uint4 = 256 B)
#pragma unroll
        for (int n = 0; n < 4; ++n) {
            int r = wave * 4 + n;
            int i = row0 + r;
            float acc[8];
#pragma unroll
            for (int t = 0; t < 8; ++t) acc[t] = 0.f;
            int e0 = e0s[n], e1 = e1s[n];
            for (int base = e0; base < e1; base += 64) {
                int rem64 = e1 - base;
                int cnt = rem64 < 64 ? rem64 : 64;
                int idx = (base + lane < e1) ? cs[base + lane] : 0;
                int j = 0;
                for (; j + 16 <= cnt; j += 16) {   // 4 loads = 16 edges
                    int s0 = __shfl(idx, j + q, 64);
                    int s1 = __shfl(idx, j + 4 + q, 64);
                    int s2 = __shfl(idx, j + 8 + q, 64);
                    int s3 = __shfl(idx, j + 12 + q, 64);
                    uint4 v0 = hbp[(size_t)s0 * 32 + ql];
                    uint4 v1 = hbp[(size_t)s1 * 32 + ql];
                    uint4 v2 = hbp[(size_t)s2 * 32 + ql];
                    uint4 v3 = hbp[(size_t)s3 * 32 + ql];
                    ACCV(v0); ACCV(v1); ACCV(v2); ACCV(v3);
                }
                for (; j + 4 <= cnt; j += 4) {     // 1 load = 4 edges
                    int s = __shfl(idx, j + q, 64);
                    uint4 v = hbp[(size_t)s * 32 + ql];
                    ACCV(v);
                }
                int rem = cnt - j;                  // 0..3 edges
                // FIX: shfl executed by ALL lanes; source lane j + (q<rem?q:0)
                // is always < cnt (active). Only the load is guarded.
                int srcl = j + (q < rem ? q : 0);
                int s = __shfl(idx, srcl, 64);
                if (q < rem) {
                    uint4 v = hbp[(size_t)s * 32 + ql];
                    ACCV(v);
                }
            }
            // cross-quarter reduce: all lanes end with the half-row sums
#pragma unroll
            for (int t = 0; t < 8; ++t) {
                acc[t] += __shfl_xor(acc[t], 16, 64);
                acc[t] += __shfl_xor(acc[t], 32, 64);
            }
            if (q == 0) {
                uint4 sv = hbp[(size_t)i * 32 + ql];   // self half-row
                acc[0] += bfbits2f(sv.x << 16) * sc; acc[1] += bfbits2f(sv.x & 0xffff0000u) * sc;
                acc[2] += bfbits2f(sv.y << 16) * sc; acc[3] += bfbits2f(sv.y & 0xffff0000u) * sc;
                acc[4] += bfbits2f(sv.z << 16) * sc; acc[5] += bfbits2f(sv.z & 0xffff0000u) * sc;
                acc[6] += bfbits2f(sv.w << 16) * sc; acc[7] += bfbits2f(sv.w & 0xffff0000u) * sc;
                uint4 o;
                o.x = (uint)f2bf(acc[0]) | ((uint)f2bf(acc[1]) << 16);
                o.y = (uint)f2bf(acc[2]) | ((uint)f2bf(acc[3]) << 16);
                o.z = (uint)f2bf(acc[4]) | ((uint)f2bf(acc[5]) << 16);
                o.w = (uint)f2bf(acc[6]) | ((uint)f2bf(acc[7]) << 16);
                *(uint4*)&As[r][p * 128 + ql * 8] = o;
            }
        }
    }
    __syncthreads();

    // ---- GEMM1: t = relu(As@W1 + b1), BK=64 ----
    f32x4 acc4[4];
#pragma unroll
    for (int t = 0; t < 4; ++t) acc4[t] = (f32x4){0.f, 0.f, 0.f, 0.f};
    for (int k0 = 0; k0 < DIM; k0 += 64) {
#pragma unroll
        for (int j = 0; j < 8; ++j) {   // stage 256x64 B slice
            int rr = srow2 + 32 * j;
            *(uint4*)&Bs[rr][skol2] = *(const uint4*)&Wt1[(size_t)rr * DIM + k0 + skol2];
        }
        __syncthreads();
#pragma unroll
        for (int kk = 0; kk < 2; ++kk) {
            bf16x8 af = *(const bf16x8*)&As[l16][k0 + kk * 32 + quad * 8];
#pragma unroll
            for (int tj = 0; tj < 4; ++tj) {
                bf16x8 bfv = *(const bf16x8*)&Bs[wc + tj * 16 + l16][kk * 32 + quad * 8];
                acc4[tj] = __builtin_amdgcn_mfma_f32_16x16x32_bf16(af, bfv, acc4[tj], 0, 0, 0);
            }
        }
        __syncthreads();
    }
    // write t into As-space (WAR-safe: loop-exit barrier above)
#pragma unroll
    for (int tj = 0; tj < 4; ++tj) {
        int col = wc + tj * 16 + l16;
        float bias = b1[col];
#pragma unroll
        for (int r = 0; r < 4; ++r)
            As[quad * 4 + r][col] = f2bf(fmaxf(acc4[tj][r] + bias, 0.f));
    }
    __syncthreads();

    // ---- GEMM2: h = relu(bn(t@W2)), BK=64, t read from As-space ----
#pragma unroll
    for (int t = 0; t < 4; ++t) acc4[t] = (f32x4){0.f, 0.f, 0.f, 0.f};
    for (int k0 = 0; k0 < DIM; k0 += 64) {
#pragma unroll
        for (int j = 0; j < 8; ++j) {
            int rr = srow2 + 32 * j;
            *(uint4*)&Bs[rr][skol2] = *(const uint4*)&Wt2[(size_t)rr * DIM + k0 + skol2];
        }
        __syncthreads();
#pragma unroll
        for (int kk = 0; kk < 2; ++kk) {
            bf16x8 af = *(const bf16x8*)&As[l16][k0 + kk * 32 + quad * 8];
#pragma unroll
            for (int tj = 0; tj < 4; ++tj) {
                bf16x8 bfv = *(const bf16x8*)&Bs[wc + tj * 16 + l16][kk * 32 + quad * 8];
                acc4[tj] = __builtin_amdgcn_mfma_f32_16x16x32_bf16(af, bfv, acc4[tj], 0, 0, 0);
            }
        }
        __syncthreads();
    }
#pragma unroll
    for (int tj = 0; tj < 4; ++tj) {
        int col = wc + tj * 16 + l16;
        float s = bnsc[col], sh = bnsh[col];
#pragma unroll
        for (int r = 0; r < 4; ++r) {
            int row = row0 + quad * 4 + r;
            float v = fmaxf(acc4[tj][r] * s + sh, 0.f);
            if (outF) outF[(size_t)row * DIM + col] = v;
            if (outB) outB[(size_t)row * DIM + col] = f2bf(v);
        }
    }
}

// ---------------- pooling: batch sorted -> per-graph contiguous range -------
__global__ __launch_bounds__(256)
void pool_kernel(const float* __restrict__ hfin, const int* __restrict__ batch,
                 float* __restrict__ out) {
    int g = blockIdx.x;
    int d = threadIdx.x;
    int l = 0, r = N_NODES;
    while (l < r) { int m = (l + r) >> 1; if (batch[m] < g) l = m + 1; else r = m; }
    int lo = l;
    r = N_NODES;
    while (l < r) { int m = (l + r) >> 1; if (batch[m] < g + 1) l = m + 1; else r = m; }
    int hi = l;
    float a0 = 0.f, a1 = 0.f, a2 = 0.f, a3 = 0.f;
    int i = lo;
    for (; i + 4 <= hi; i += 4) {
        a0 += hfin[(size_t)i * DIM + d];
        a1 += hfin[(size_t)(i + 1) * DIM + d];
        a2 += hfin[(size_t)(i + 2) * DIM + d];
        a3 += hfin[(size_t)(i + 3) * DIM + d];
    }
    for (; i < hi; ++i) a0 += hfin[(size_t)i * DIM + d];
    float c = (float)(hi - lo);
    if (c < 1.f) c = 1.f;
    out[g * DIM + d] = ((a0 + a1) + (a2 + a3)) / c;
}

// ---------------- launch ----------------
extern "C" void kernel_launch(void* const* d_in, const int* in_sizes, int n_in,
                              void* d_out, int out_size, void* d_ws, size_t ws_size,
                              hipStream_t stream) {
    const int*   feat_id  = (const int*)d_in[0];
    const int*   ei       = (const int*)d_in[1];
    const int*   batch    = (const int*)d_in[2];
    const float* rwse     = (const float*)d_in[3];
    const int*   in_deg   = (const int*)d_in[4];
    const float* w_val    = (const float*)d_in[5];
    const float* b_val    = (const float*)d_in[6];
    const float* w_rwse   = (const float*)d_in[7];
    const float* b_rwse   = (const float*)d_in[8];
    const float* deg_emb  = (const float*)d_in[9];
    const float* mlp_w1   = (const float*)d_in[10];
    const float* mlp_b1   = (const float*)d_in[11];
    const float* mlp_w2   = (const float*)d_in[12];
    const float* mlp_b2   = (const float*)d_in[13];
    const float* bn_gamma = (const float*)d_in[14];
    const float* bn_beta  = (const float*)d_in[15];
    const float* bn_mean  = (const float*)d_in[16];
    const float* bn_var   = (const float*)d_in[17];
    const float* eps_gin  = (const float*)d_in[18];

    float* out = (float*)d_out;
    float* out_h = out + N_GRAPHS * DIM;   // final h (f32) written by last layer

    char* w = (char*)d_ws;
    ushort* hb0  = (ushort*)w;                                // N*D bf16 (even layers in)
    ushort* hb1  = hb0 + (size_t)N_NODES * DIM;               // N*D bf16 (odd layers in)
    ushort* wt1  = hb1 + (size_t)N_NODES * DIM;               // L*D*D bf16
    ushort* wt2  = wt1 + (size_t)N_LAYERS * DIM * DIM;        // L*D*D bf16
    int* cnt_arr = (int*)(wt2 + (size_t)N_LAYERS * DIM * DIM); // N
    int* cur     = cnt_arr + N_NODES;                         // N
    int* cs      = cur + N_NODES;                             // E
    float* bnsc  = (float*)(cs + N_EDGES);                    // L*D
    float* bnsh  = bnsc + N_LAYERS * DIM;                     // L*D

    hipMemsetAsync(cnt_arr, 0, N_NODES * sizeof(int), stream);

    setup_kernel<<<11895, 256, 0, stream>>>(
        feat_id, rwse, in_deg, w_val, b_val, w_rwse, b_rwse, deg_emb,
        hb0, ei, cnt_arr, mlp_w1, mlp_w2, wt1, wt2,
        bn_gamma, bn_beta, bn_mean, bn_var, mlp_b2, bnsc, bnsh);
    scan_kernel<<<1, 1024, 0, stream>>>(cnt_arr, cur, N_NODES);
    fill_kernel<<<(N_EDGES + 255) / 256, 256, 0, stream>>>(ei, cur, cs);

    int ggrid = N_NODES / GBM;   // 625, exact
    for (int l = 0; l < N_LAYERS; ++l) {
        bool last = (l == N_LAYERS - 1);
        const ushort* hin = (l & 1) ? hb1 : hb0;
        ushort* hout = (l & 1) ? hb0 : hb1;
        layer_kernel<<<ggrid, 256, 0, stream>>>(
            hin, cur, cs, eps_gin, l,
            wt1 + (size_t)l * DIM * DIM, mlp_b1 + l * DIM,
            wt2 + (size_t)l * DIM * DIM, bnsc + l * DIM, bnsh + l * DIM,
            last ? out_h : nullptr, last ? nullptr : hout);
    }

    pool_kernel<<<N_GRAPHS, 256, 0, stream>>>(out_h, batch, out);
}

// Round 11
// 314.938 us; speedup vs baseline: 1.0852x; 1.0852x over previous
//
#include <hip/hip_runtime.h>
#include <hip/hip_bf16.h>

#define N_NODES 10000
#define N_EDGES 320000
#define DIM     256
#define N_LAYERS 5
#define N_GRAPHS 128
#define RWSE_K  16
#define GBM 16

typedef __bf16 bf16_t;
typedef bf16_t bf16x8 __attribute__((ext_vector_type(8)));
typedef float  f32x4  __attribute__((ext_vector_type(4)));

__device__ inline ushort f2bf(float f) {
    union { float f; unsigned u; } v; v.f = f;
    unsigned r = v.u + 0x7fff + ((v.u >> 16) & 1);
    return (ushort)(r >> 16);
}
__device__ inline float bfbits2f(unsigned hi16) {
    union { unsigned u; float f; } v; v.u = hi16;
    return v.f;
}

// ---------------- fused setup: embed + edge-count + weight conv + BN fold
//                  + per-graph inverse counts (for fused pooling) ------------
__global__ __launch_bounds__(256)
void setup_kernel(const int* __restrict__ feat_id,
                  const float* __restrict__ rwse,
                  const int* __restrict__ in_deg,
                  const float* __restrict__ w_val,
                  const float* __restrict__ b_val,
                  const float* __restrict__ w_rwse,
                  const float* __restrict__ b_rwse,
                  const float* __restrict__ deg_emb,
                  ushort* __restrict__ hb,
                  const int* __restrict__ ei, int* __restrict__ cnt_arr,
                  const float* __restrict__ w1, const float* __restrict__ w2,
                  ushort* __restrict__ wt1, ushort* __restrict__ wt2,
                  const float* __restrict__ gamma, const float* __restrict__ beta,
                  const float* __restrict__ mean, const float* __restrict__ var,
                  const float* __restrict__ b2, float* __restrict__ scale,
                  float* __restrict__ shift,
                  const int* __restrict__ batch, float* __restrict__ invcnt) {
    __shared__ float r[RWSE_K];
    __shared__ float t[32][33];
    int b = blockIdx.x;
    int tid = threadIdx.x;
    if (b < N_NODES) {
        int i = b, d = tid;
        if (d < RWSE_K) r[d] = rwse[i * RWSE_K + d];
        __syncthreads();
        int hid = feat_id[i] & (DIM - 1);
        int dg = in_deg[i];
        dg = dg < 0 ? 0 : (dg > 1000 ? 1000 : dg);
        float v = w_val[hid * DIM + d] + b_val[d] + b_rwse[d] + deg_emb[dg * DIM + d];
#pragma unroll
        for (int k = 0; k < RWSE_K; ++k) v += r[k] * w_rwse[k * DIM + d];
        hb[i * DIM + d] = f2bf(v);
    } else if (b < 11250) {
        int e = (b - N_NODES) * 256 + tid;
        if (e < N_EDGES) atomicAdd(&cnt_arr[ei[N_EDGES + e]], 1);
    } else if (b < 11890) {
        int w_id = b - 11250;
        int l = w_id >> 7;
        int rem = w_id & 127;
        int mat = rem >> 6;
        int tile = rem & 63;
        const float* W  = (mat ? w2  : w1)  + (size_t)l * DIM * DIM;
        ushort*      Wt = (mat ? wt2 : wt1) + (size_t)l * DIM * DIM;
        int k0 = (tile >> 3) * 32, n0 = (tile & 7) * 32;
        int tx = tid & 31, ty = tid >> 5;
#pragma unroll
        for (int j = 0; j < 4; ++j)
            t[ty + j * 8][tx] = W[(k0 + ty + j * 8) * DIM + n0 + tx];
        __syncthreads();
#pragma unroll
        for (int j = 0; j < 4; ++j)
            Wt[(n0 + ty + j * 8) * DIM + k0 + tx] = f2bf(t[tx][ty + j * 8]);
    } else if (b < 11895) {
        int l = b - 11890;
        int idx = l * DIM + tid;
        float s = gamma[idx] * rsqrtf(var[idx] + 1e-5f);
        scale[idx] = s;
        shift[idx] = beta[idx] + (b2[idx] - mean[idx]) * s;
    } else {
        // per-graph inverse counts (batch is sorted)
        int g = tid;
        if (g < N_GRAPHS) {
            int l = 0, rr = N_NODES;
            while (l < rr) { int m = (l + rr) >> 1; if (batch[m] < g) l = m + 1; else rr = m; }
            int lo = l;
            rr = N_NODES;
            while (l < rr) { int m = (l + rr) >> 1; if (batch[m] < g + 1) l = m + 1; else rr = m; }
            int c = l - lo;
            invcnt[g] = 1.0f / (float)(c < 1 ? 1 : c);
        }
    }
}

// exclusive scan of cnt_arr into cur (single block, wave-shuffle based)
__global__ __launch_bounds__(1024)
void scan_kernel(const int* __restrict__ cnt_arr, int* __restrict__ cur, int n) {
    __shared__ int wsum[16];
    __shared__ int carry_sh;
    int tid = threadIdx.x, wave = tid >> 6, lane = tid & 63;
    if (tid == 0) carry_sh = 0;
    __syncthreads();
    for (int base = 0; base < n; base += 1024) {
        int idx = base + tid;
        int v = (idx < n) ? cnt_arr[idx] : 0;
        int s = v;
#pragma unroll
        for (int off = 1; off < 64; off <<= 1) {
            int t = __shfl_up(s, off, 64);
            if (lane >= off) s += t;
        }
        if (lane == 63) wsum[wave] = s;
        __syncthreads();
        if (wave == 0) {
            int ws = (lane < 16) ? wsum[lane] : 0;
#pragma unroll
            for (int off = 1; off < 16; off <<= 1) {
                int t = __shfl_up(ws, off, 64);
                if (lane >= off) ws += t;
            }
            if (lane < 16) wsum[lane] = ws;
        }
        __syncthreads();
        int excl = s - v + (wave ? wsum[wave - 1] : 0) + carry_sh;
        if (idx < n) cur[idx] = excl;
        __syncthreads();
        if (tid == 0) carry_sh += wsum[15];
        __syncthreads();
    }
}

__global__ __launch_bounds__(256)
void fill_kernel(const int* __restrict__ ei, int* __restrict__ cur,
                 int* __restrict__ cs) {
    int e = blockIdx.x * 256 + threadIdx.x;
    if (e < N_EDGES) {
        int d = ei[N_EDGES + e];
        int p = atomicAdd(&cur[d], 1);
        cs[p] = ei[e];
    }
}

// ---------------- fused layer: aggregation + MLP + BN + ReLU (+pool) --------
// R6-proven structure: block = 16 rows x 256 cols, 4 waves; grid 625; BK=64;
// GEMM1 output t OVERLAYS As. LAST LAYER additionally pools: per-row
// pre-scaled (x 1/cnt_g) values go to an LDS f32 tile (overlays dead Bs),
// then per-column threads reduce same-graph row runs (batch sorted) and emit
// 1-3 atomicAdds per column. Removes the pool_kernel dispatch + out_h re-read.
#define ACCV(v)                                                        \
    acc[0] += bfbits2f((v).x << 16); acc[1] += bfbits2f((v).x & 0xffff0000u); \
    acc[2] += bfbits2f((v).y << 16); acc[3] += bfbits2f((v).y & 0xffff0000u); \
    acc[4] += bfbits2f((v).z << 16); acc[5] += bfbits2f((v).z & 0xffff0000u); \
    acc[6] += bfbits2f((v).w << 16); acc[7] += bfbits2f((v).w & 0xffff0000u);

__global__ __launch_bounds__(256)
void layer_kernel(const ushort* __restrict__ hb_in,
                  const int* __restrict__ cur, const int* __restrict__ cs,
                  const float* __restrict__ eps_gin, int layer,
                  const ushort* __restrict__ Wt1, const float* __restrict__ b1,
                  const ushort* __restrict__ Wt2,
                  const float* __restrict__ bnsc, const float* __restrict__ bnsh,
                  float* __restrict__ outF, ushort* __restrict__ outB,
                  const int* __restrict__ batch, const float* __restrict__ invcnt,
                  float* __restrict__ poolOut) {
    __shared__ __align__(16) ushort As[GBM][DIM + 8];   // gather out / t overlay
    __shared__ __align__(16) ushort Bs[DIM][72];        // 256x64 weight slice / pool tile
    __shared__ int   g_sh[GBM];
    __shared__ float sc_sh[GBM];
    int tx = threadIdx.x;
    int row0 = blockIdx.x * GBM;
    int wave = tx >> 6, lane = tx & 63, quad = lane >> 4, l16 = lane & 15;
    int half = lane >> 5, sl = lane & 31;
    int wc = wave * 64;
    int srow2 = tx >> 3;           // 0..31
    int skol2 = (tx & 7) * 8;      // 0,8,...,56
    const uint4* hb4 = (const uint4*)hb_in;   // row = 32 uint4
    float sc = 1.0f + eps_gin[layer];

    if (poolOut && tx < GBM) {     // graph id + pre-scale per row (last layer)
        int gg = batch[row0 + tx];
        g_sh[tx] = gg;
        sc_sh[tx] = invcnt[gg];
    }

    // ---- Phase A: aggregate this block's 16 rows into As ----
#pragma unroll
    for (int n = 0; n < 4; ++n) {
        int r = wave * 4 + n;
        int i = row0 + r;          // always < N_NODES (exact grid)
        float acc[8];
#pragma unroll
        for (int t = 0; t < 8; ++t) acc[t] = 0.f;
        int e0 = i ? cur[i - 1] : 0;
        int e1 = cur[i];
        for (int base = e0; base < e1; base += 64) {
            int rem = e1 - base;
            int cnt = rem < 64 ? rem : 64;
            int idx = (base + lane < e1) ? cs[base + lane] : 0;
            int j = 0;
            for (; j + 8 <= cnt; j += 8) {
                int s0 = __shfl(idx, j + half, 64);
                int s1 = __shfl(idx, j + 2 + half, 64);
                int s2 = __shfl(idx, j + 4 + half, 64);
                int s3 = __shfl(idx, j + 6 + half, 64);
                uint4 v0 = hb4[(size_t)s0 * 32 + sl];
                uint4 v1 = hb4[(size_t)s1 * 32 + sl];
                uint4 v2 = hb4[(size_t)s2 * 32 + sl];
                uint4 v3 = hb4[(size_t)s3 * 32 + sl];
                ACCV(v0); ACCV(v1); ACCV(v2); ACCV(v3);
            }
            for (; j + 2 <= cnt; j += 2) {
                int s = __shfl(idx, j + half, 64);
                uint4 v = hb4[(size_t)s * 32 + sl];
                ACCV(v);
            }
            if (j < cnt) {
                int s = __shfl(idx, j, 64);
                if (half == 0) {
                    uint4 v = hb4[(size_t)s * 32 + sl];
                    ACCV(v);
                }
            }
        }
#pragma unroll
        for (int t = 0; t < 8; ++t) acc[t] += __shfl_xor(acc[t], 32, 64);
        if (half == 0) {
            uint4 sv = hb4[(size_t)i * 32 + sl];   // self term (bf16)
            acc[0] += bfbits2f(sv.x << 16) * sc; acc[1] += bfbits2f(sv.x & 0xffff0000u) * sc;
            acc[2] += bfbits2f(sv.y << 16) * sc; acc[3] += bfbits2f(sv.y & 0xffff0000u) * sc;
            acc[4] += bfbits2f(sv.z << 16) * sc; acc[5] += bfbits2f(sv.z & 0xffff0000u) * sc;
            acc[6] += bfbits2f(sv.w << 16) * sc; acc[7] += bfbits2f(sv.w & 0xffff0000u) * sc;
            uint4 o;
            o.x = (uint)f2bf(acc[0]) | ((uint)f2bf(acc[1]) << 16);
            o.y = (uint)f2bf(acc[2]) | ((uint)f2bf(acc[3]) << 16);
            o.z = (uint)f2bf(acc[4]) | ((uint)f2bf(acc[5]) << 16);
            o.w = (uint)f2bf(acc[6]) | ((uint)f2bf(acc[7]) << 16);
            *(uint4*)&As[r][sl * 8] = o;
        }
    }
    __syncthreads();

    // ---- GEMM1: t = relu(As@W1 + b1), BK=64 ----
    f32x4 acc4[4];
#pragma unroll
    for (int t = 0; t < 4; ++t) acc4[t] = (f32x4){0.f, 0.f, 0.f, 0.f};
    for (int k0 = 0; k0 < DIM; k0 += 64) {
#pragma unroll
        for (int j = 0; j < 8; ++j) {   // stage 256x64 B slice
            int rr = srow2 + 32 * j;
            *(uint4*)&Bs[rr][skol2] = *(const uint4*)&Wt1[(size_t)rr * DIM + k0 + skol2];
        }
        __syncthreads();
#pragma unroll
        for (int kk = 0; kk < 2; ++kk) {
            bf16x8 af = *(const bf16x8*)&As[l16][k0 + kk * 32 + quad * 8];
#pragma unroll
            for (int tj = 0; tj < 4; ++tj) {
                bf16x8 bfv = *(const bf16x8*)&Bs[wc + tj * 16 + l16][kk * 32 + quad * 8];
                acc4[tj] = __builtin_amdgcn_mfma_f32_16x16x32_bf16(af, bfv, acc4[tj], 0, 0, 0);
            }
        }
        __syncthreads();
    }
    // write t into As-space (WAR-safe: loop-exit barrier above)
#pragma unroll
    for (int tj = 0; tj < 4; ++tj) {
        int col = wc + tj * 16 + l16;
        float bias = b1[col];
#pragma unroll
        for (int r = 0; r < 4; ++r)
            As[quad * 4 + r][col] = f2bf(fmaxf(acc4[tj][r] + bias, 0.f));
    }
    __syncthreads();

    // ---- GEMM2: h = relu(bn(t@W2)), BK=64, t read from As-space ----
#pragma unroll
    for (int t = 0; t < 4; ++t) acc4[t] = (f32x4){0.f, 0.f, 0.f, 0.f};
    for (int k0 = 0; k0 < DIM; k0 += 64) {
#pragma unroll
        for (int j = 0; j < 8; ++j) {
            int rr = srow2 + 32 * j;
            *(uint4*)&Bs[rr][skol2] = *(const uint4*)&Wt2[(size_t)rr * DIM + k0 + skol2];
        }
        __syncthreads();
#pragma unroll
        for (int kk = 0; kk < 2; ++kk) {
            bf16x8 af = *(const bf16x8*)&As[l16][k0 + kk * 32 + quad * 8];
#pragma unroll
            for (int tj = 0; tj < 4; ++tj) {
                bf16x8 bfv = *(const bf16x8*)&Bs[wc + tj * 16 + l16][kk * 32 + quad * 8];
                acc4[tj] = __builtin_amdgcn_mfma_f32_16x16x32_bf16(af, bfv, acc4[tj], 0, 0, 0);
            }
        }
        __syncthreads();
    }
    // Bs is dead past here (last read above, behind the loop-exit barrier).
    float* Pf = (float*)&Bs[0][0];     // pool tile [16][stride 260] f32
#pragma unroll
    for (int tj = 0; tj < 4; ++tj) {
        int col = wc + tj * 16 + l16;
        float s = bnsc[col], sh = bnsh[col];
#pragma unroll
        for (int r = 0; r < 4; ++r) {
            int row = row0 + quad * 4 + r;
            float v = fmaxf(acc4[tj][r] * s + sh, 0.f);
            if (outF) outF[(size_t)row * DIM + col] = v;
            if (outB) outB[(size_t)row * DIM + col] = f2bf(v);
            if (poolOut) Pf[(quad * 4 + r) * 260 + col] = v * sc_sh[quad * 4 + r];
        }
    }
    if (poolOut) {
        __syncthreads();
        // per-column run reduction over the block's 16 rows (batch sorted)
        int gcur = g_sh[0];
        float ssum = 0.f;
#pragma unroll
        for (int rr = 0; rr < GBM; ++rr) {
            if (g_sh[rr] != gcur) {
                atomicAdd(&poolOut[(size_t)gcur * DIM + tx], ssum);
                gcur = g_sh[rr];
                ssum = 0.f;
            }
            ssum += Pf[rr * 260 + tx];
        }
        atomicAdd(&poolOut[(size_t)gcur * DIM + tx], ssum);
    }
}

// ---------------- launch ----------------
extern "C" void kernel_launch(void* const* d_in, const int* in_sizes, int n_in,
                              void* d_out, int out_size, void* d_ws, size_t ws_size,
                              hipStream_t stream) {
    const int*   feat_id  = (const int*)d_in[0];
    const int*   ei       = (const int*)d_in[1];
    const int*   batch    = (const int*)d_in[2];
    const float* rwse     = (const float*)d_in[3];
    const int*   in_deg   = (const int*)d_in[4];
    const float* w_val    = (const float*)d_in[5];
    const float* b_val    = (const float*)d_in[6];
    const float* w_rwse   = (const float*)d_in[7];
    const float* b_rwse   = (const float*)d_in[8];
    const float* deg_emb  = (const float*)d_in[9];
    const float* mlp_w1   = (const float*)d_in[10];
    const float* mlp_b1   = (const float*)d_in[11];
    const float* mlp_w2   = (const float*)d_in[12];
    const float* mlp_b2   = (const float*)d_in[13];
    const float* bn_gamma = (const float*)d_in[14];
    const float* bn_beta  = (const float*)d_in[15];
    const float* bn_mean  = (const float*)d_in[16];
    const float* bn_var   = (const float*)d_in[17];
    const float* eps_gin  = (const float*)d_in[18];

    float* out = (float*)d_out;
    float* out_h = out + N_GRAPHS * DIM;   // final h (f32) written by last layer

    char* w = (char*)d_ws;
    ushort* hb0  = (ushort*)w;                                // N*D bf16 (even layers in)
    ushort* hb1  = hb0 + (size_t)N_NODES * DIM;               // N*D bf16 (odd layers in)
    ushort* wt1  = hb1 + (size_t)N_NODES * DIM;               // L*D*D bf16
    ushort* wt2  = wt1 + (size_t)N_LAYERS * DIM * DIM;        // L*D*D bf16
    int* cnt_arr = (int*)(wt2 + (size_t)N_LAYERS * DIM * DIM); // N
    int* cur     = cnt_arr + N_NODES;                         // N
    int* cs      = cur + N_NODES;                             // E
    float* bnsc  = (float*)(cs + N_EDGES);                    // L*D
    float* bnsh  = bnsc + N_LAYERS * DIM;                     // L*D
    float* invcnt = bnsh + N_LAYERS * DIM;                    // G

    hipMemsetAsync(cnt_arr, 0, N_NODES * sizeof(int), stream);

    setup_kernel<<<11896, 256, 0, stream>>>(
        feat_id, rwse, in_deg, w_val, b_val, w_rwse, b_rwse, deg_emb,
        hb0, ei, cnt_arr, mlp_w1, mlp_w2, wt1, wt2,
        bn_gamma, bn_beta, bn_mean, bn_var, mlp_b2, bnsc, bnsh,
        batch, invcnt);
    scan_kernel<<<1, 1024, 0, stream>>>(cnt_arr, cur, N_NODES);
    fill_kernel<<<(N_EDGES + 255) / 256, 256, 0, stream>>>(ei, cur, cs);

    int ggrid = N_NODES / GBM;   // 625, exact
    for (int l = 0; l < N_LAYERS; ++l) {
        bool last = (l == N_LAYERS - 1);
        const ushort* hin = (l & 1) ? hb1 : hb0;
        ushort* hout = (l & 1) ? hb0 : hb1;
        layer_kernel<<<ggrid, 256, 0, stream>>>(
            hin, cur, cs, eps_gin, l,
            wt1 + (size_t)l * DIM * DIM, mlp_b1 + l * DIM,
            wt2 + (size_t)l * DIM * DIM, bnsc + l * DIM, bnsh + l * DIM,
            last ? out_h : nullptr, last ? nullptr : hout,
            batch, invcnt, last ? out : nullptr);
    }
}